// Round 4
// baseline (654.660 us; speedup 1.0000x reference)
//
#include <hip/hip_runtime.h>

#define T_LEN   262144
#define NV      20
#define NE      30
#define NH      40
#define NG      160                    // 4*NH
#define CHUNK   512
#define WARM    64
#define SPC     (WARM + CHUNK)         // 576
#define NBLK    (T_LEN / CHUNK)        // 512
#define SS      32                     // steps per super-step
#define NSS     (SPC / SS)             // 18
#define WUSS    (WARM / SS)            // 2
#define NTHR    192

__device__ __forceinline__ float sig_(float x) {
    x = fminf(fmaxf(x, -30.f), 30.f);
    return __fdividef(1.f, 1.f + __expf(-x));
}
__device__ __forceinline__ float tanh_(float x) {
    x = fminf(fmaxf(x, -15.f), 15.f);
    float e = __expf(2.f * x);
    return __fdividef(e - 1.f, e + 1.f);
}
__device__ __forceinline__ float rl_(int v, int l) {
    return __int_as_float(__builtin_amdgcn_readlane(v, l));
}

// 10 named float4 per gate; KEEP makes the loaded values opaque so the
// register allocator cannot rematerialize (re-load) them inside the step loop.
#define DECL10(V) float4 V##0, V##1, V##2, V##3, V##4, V##5, V##6, V##7, V##8, V##9
#define LOAD10(V, P) do { const float4* _p = (const float4*)(P); \
    V##0=_p[0]; V##1=_p[1]; V##2=_p[2]; V##3=_p[3]; V##4=_p[4]; \
    V##5=_p[5]; V##6=_p[6]; V##7=_p[7]; V##8=_p[8]; V##9=_p[9]; } while(0)
#define KEEP4(v)  asm volatile("" : "+v"((v).x), "+v"((v).y), "+v"((v).z), "+v"((v).w))
#define KEEP10(V) do { KEEP4(V##0); KEEP4(V##1); KEEP4(V##2); KEEP4(V##3); KEEP4(V##4); \
                       KEEP4(V##5); KEEP4(V##6); KEEP4(V##7); KEEP4(V##8); KEEP4(V##9); } while(0)

#define ACCQ(Q) do { \
    const float e0 = rl_(hb, 4*Q+0); \
    const float e1 = rl_(hb, 4*Q+1); \
    const float e2 = rl_(hb, 4*Q+2); \
    const float e3 = rl_(hb, 4*Q+3); \
    ai = fmaf(e0, wi##Q.x, ai); af = fmaf(e0, wf##Q.x, af); \
    ag = fmaf(e0, wg##Q.x, ag); ao = fmaf(e0, wo##Q.x, ao); \
    ai = fmaf(e1, wi##Q.y, ai); af = fmaf(e1, wf##Q.y, af); \
    ag = fmaf(e1, wg##Q.y, ag); ao = fmaf(e1, wo##Q.y, ao); \
    ai = fmaf(e2, wi##Q.z, ai); af = fmaf(e2, wf##Q.z, af); \
    ag = fmaf(e2, wg##Q.z, ag); ao = fmaf(e2, wo##Q.z, ao); \
    ai = fmaf(e3, wi##Q.w, ai); af = fmaf(e3, wf##Q.w, af); \
    ag = fmaf(e3, wg##Q.w, ag); ao = fmaf(e3, wo##Q.w, ao); \
} while(0)

#define LDOT(Q) do { float4 hv = hr[Q]; \
    acc0 = fmaf(hv.x, wi##Q.x, acc0); acc1 = fmaf(hv.y, wi##Q.y, acc1); \
    acc0 = fmaf(hv.z, wi##Q.z, acc0); acc1 = fmaf(hv.w, wi##Q.w, acc1); } while(0)

// Wave roles per block (192 thr = 3 waves):
//   wave 0/1: LSTM cell per direction — lane k holds h_k,c_k and W_hh rows for
//             unit k in 160 register-pinned floats; h broadcast via v_readlane.
//   wave 2:   logits — consumes 32-step h batches from a double-buffered LDS
//             ring; one barrier per 32 steps.
extern "C" __global__ void __launch_bounds__(NTHR, 1)
bilstm_kernel(const int* __restrict__ tokens,
              const float* __restrict__ embed,
              const float* __restrict__ W_ih1, const float* __restrict__ W_hh1,
              const float* __restrict__ b_ih1, const float* __restrict__ b_hh1,
              const float* __restrict__ W_ih2, const float* __restrict__ W_hh2,
              const float* __restrict__ b_ih2, const float* __restrict__ b_hh2,
              const float* __restrict__ W_l1,  const float* __restrict__ b_l1,
              const float* __restrict__ W_l2,  const float* __restrict__ b_l2,
              float* __restrict__ out)
{
    __shared__ __align__(16) float tab[2 * NV * NH * 4];   // [d][v][k][gate]
    __shared__ __align__(16) float ring[2][2][SS][64];     // [parity][d][sl][lane]
    __shared__ __align__(16) float embS[NV * NE];
    __shared__ int tokS[2][SPC];

    const int tid  = threadIdx.x;
    const int wave = tid >> 6;
    const int lane = tid & 63;
    const int a    = blockIdx.x * CHUNK;

    // ---- stage embed + tokens ----
    for (int p = tid; p < NV * NE; p += NTHR) embS[p] = embed[p];
    for (int p = tid; p < SPC; p += NTHR) {
        int t = a - WARM + p;
        if (t >= 0) {
            tokS[0][p] = tokens[t];
            tokS[1][p] = tokens[T_LEN - 1 - t];
        }
    }
    __syncthreads();

    // ---- x-pre tables: tab[((d*NV+v)*NH+k)*4+g] = emb[v]·W_ih[g*NH+k] + b_ih+b_hh ----
    for (int p = tid; p < 2 * NV * NG; p += NTHR) {
        int g = p & 3, r = p >> 2;
        int k = r % NH, q = r / NH;
        int v = q % NV, dd = q / NV;
        const float* Wih = dd ? W_ih2 : W_ih1;
        const float* bi  = dd ? b_ih2 : b_ih1;
        const float* bh  = dd ? b_hh2 : b_hh1;
        int j = g * NH + k;
        float acc = bi[j] + bh[j];
        #pragma unroll
        for (int e = 0; e < NE; ++e) acc += embS[v * NE + e] * Wih[j * NE + e];
        tab[p] = acc;
    }

    // ---- per-wave weights pinned in registers ----
    const bool isCell = (wave < 2);
    const int  dir    = wave;
    const int  kk     = (lane < NH) ? lane : NH - 1;

    DECL10(wi); DECL10(wf); DECL10(wg); DECL10(wo);
    float lb = 0.f;
    if (isCell) {
        const float* Whh = dir ? W_hh2 : W_hh1;
        LOAD10(wi, Whh + (0 * NH + kk) * NH);
        LOAD10(wf, Whh + (1 * NH + kk) * NH);
        LOAD10(wg, Whh + (2 * NH + kk) * NH);
        LOAD10(wo, Whh + (3 * NH + kk) * NH);
        KEEP10(wi); KEEP10(wf); KEEP10(wg); KEEP10(wo);
        __builtin_amdgcn_s_setprio(1);           // cell waves are the critical path
    } else {
        int half = lane >> 5, v = lane & 31;
        int vv   = (v < NV) ? v : NV - 1;
        const float* Wl = half ? W_l2 : W_l1;
        LOAD10(wi, Wl + vv * NH);                // logit wave reuses wi names
        KEEP10(wi);
        if (!half) lb = b_l1[vv] + b_l2[vv];
    }
    __syncthreads();   // tab + tokS ready

    // ---- cell init + first x-pre prefetch ----
    const int cell_ss0 = (a < WARM) ? WUSS : 0;  // block 0 starts exactly at s=WARM
    float h = 0.f, c = 0.f;
    float x0 = 0.f, x1 = 0.f, x2 = 0.f, x3 = 0.f;
    if (isCell) {
        int tk = tokS[dir][cell_ss0 * SS];
        float4 xv = *(const float4*)&tab[((dir * NV + tk) * NH + kk) * 4];
        x0 = xv.x; x1 = xv.y; x2 = xv.z; x3 = xv.w;
    }

    // ---- main loop: NSS super-steps of SS steps + 1 logit flush ----
    #pragma unroll 1
    for (int ss = 0; ss <= NSS; ++ss) {
        if (isCell && ss >= cell_ss0 && ss < NSS) {
            const int sbase = ss * SS;
            #pragma unroll 1
            for (int sl = 0; sl < SS; ++sl) {
                const int s  = sbase + sl;
                const int hb = __float_as_int(h);
                float ai = x0, af = x1, ag = x2, ao = x3;
                ACCQ(0); ACCQ(1); ACCQ(2); ACCQ(3); ACCQ(4);
                ACCQ(5); ACCQ(6); ACCQ(7); ACCQ(8); ACCQ(9);
                int sn = (s + 1 < SPC) ? s + 1 : SPC - 1;     // prefetch next x-pre
                int tk = tokS[dir][sn];
                float4 xv = *(const float4*)&tab[((dir * NV + tk) * NH + kk) * 4];
                x0 = xv.x; x1 = xv.y; x2 = xv.z; x3 = xv.w;
                float I = sig_(ai), F = sig_(af), G = tanh_(ag), O = sig_(ao);
                c = fmaf(F, c, I * G);
                h = O * tanh_(c);
                ring[ss & 1][dir][sl][lane] = h;              // padded: no lane guard
            }
        }
        if (!isCell && ss > WUSS && ss <= NSS) {
            const int b = ss - 1, par = b & 1;
            const int half = lane >> 5, v = lane & 31;
            #pragma unroll 1
            for (int sl = 0; sl < SS; ++sl) {
                const float4* hr = (const float4*)ring[par][half][sl];
                float acc0 = 0.f, acc1 = 0.f;
                LDOT(0); LDOT(1); LDOT(2); LDOT(3); LDOT(4);
                LDOT(5); LDOT(6); LDOT(7); LDOT(8); LDOT(9);
                float acc = acc0 + acc1;
                float oth = __shfl_xor(acc, 32, 64);
                if (half == 0 && v < NV) {
                    int trow = a + b * SS + sl - WARM;
                    out[(size_t)trow * NV + v] = acc + oth + lb;
                }
            }
        }
        __syncthreads();
    }
}

extern "C" void kernel_launch(void* const* d_in, const int* in_sizes, int n_in,
                              void* d_out, int out_size, void* d_ws, size_t ws_size,
                              hipStream_t stream)
{
    const int*   tokens = (const int*)  d_in[0];
    const float* embed  = (const float*)d_in[1];
    const float* W_ih1  = (const float*)d_in[2];
    const float* W_hh1  = (const float*)d_in[3];
    const float* b_ih1  = (const float*)d_in[4];
    const float* b_hh1  = (const float*)d_in[5];
    const float* W_ih2  = (const float*)d_in[6];
    const float* W_hh2  = (const float*)d_in[7];
    const float* b_ih2  = (const float*)d_in[8];
    const float* b_hh2  = (const float*)d_in[9];
    const float* W_l1   = (const float*)d_in[10];
    const float* b_l1   = (const float*)d_in[11];
    const float* W_l2   = (const float*)d_in[12];
    const float* b_l2   = (const float*)d_in[13];
    float* outp = (float*)d_out;

    hipLaunchKernelGGL(bilstm_kernel, dim3(NBLK), dim3(NTHR), 0, stream,
                       tokens, embed, W_ih1, W_hh1, b_ih1, b_hh1,
                       W_ih2, W_hh2, b_ih2, b_hh2, W_l1, b_l1, W_l2, b_l2, outp);
}

// Round 5
// 547.061 us; speedup vs baseline: 1.1967x; 1.1967x over previous
//
#include <hip/hip_runtime.h>
#include <hip/hip_fp16.h>

#define T_LEN   262144
#define NV      20
#define NE      30
#define NH      40
#define NG      160                    // 4*NH
#define CHUNK   512
#define WARM    64
#define SPC     (WARM + CHUNK)         // 576
#define NBLK    (T_LEN / CHUNK)        // 512
#define SS      32                     // steps per super-step
#define NSS     (SPC / SS)             // 18
#define WUSS    (WARM / SS)            // 2
#define NTHR    192

typedef _Float16 half2v __attribute__((ext_vector_type(2)));

__device__ __forceinline__ float sig_(float x) {
    x = fminf(fmaxf(x, -30.f), 30.f);
    return __fdividef(1.f, 1.f + __expf(-x));
}
__device__ __forceinline__ float tanh_(float x) {
    x = fminf(fmaxf(x, -15.f), 15.f);
    float e = __expf(2.f * x);
    return __fdividef(e - 1.f, e + 1.f);
}

// pack two f32 into one u32 of f16 pair
__device__ __forceinline__ unsigned pk2_(const float* p, int m) {
    unsigned a = (unsigned)__half_as_ushort(__float2half(p[2 * m]));
    unsigned b = (unsigned)__half_as_ushort(__float2half(p[2 * m + 1]));
    return a | (b << 16);
}
// f16x2 dot with f32 accumulate (v_dot2_f32_f16)
__device__ __forceinline__ float dot2_(unsigned hp, unsigned wp, float c) {
#if __has_builtin(__builtin_amdgcn_fdot2)
    return __builtin_amdgcn_fdot2(__builtin_bit_cast(half2v, hp),
                                  __builtin_bit_cast(half2v, wp), c, false);
#else
    __half2 h = __builtin_bit_cast(__half2, hp);
    __half2 w = __builtin_bit_cast(__half2, wp);
    return fmaf(__half2float(h.x), __half2float(w.x),
           fmaf(__half2float(h.y), __half2float(w.y), c));
#endif
}

// 20 named u32 scalars per weight set — plain SSA values, guaranteed promotion.
#define D20(V) unsigned V##0,V##1,V##2,V##3,V##4,V##5,V##6,V##7,V##8,V##9, \
    V##10,V##11,V##12,V##13,V##14,V##15,V##16,V##17,V##18,V##19
#define L20(V, P) do { const float* _q = (P); \
    V##0 =pk2_(_q,0);  V##1 =pk2_(_q,1);  V##2 =pk2_(_q,2);  V##3 =pk2_(_q,3); \
    V##4 =pk2_(_q,4);  V##5 =pk2_(_q,5);  V##6 =pk2_(_q,6);  V##7 =pk2_(_q,7); \
    V##8 =pk2_(_q,8);  V##9 =pk2_(_q,9);  V##10=pk2_(_q,10); V##11=pk2_(_q,11); \
    V##12=pk2_(_q,12); V##13=pk2_(_q,13); V##14=pk2_(_q,14); V##15=pk2_(_q,15); \
    V##16=pk2_(_q,16); V##17=pk2_(_q,17); V##18=pk2_(_q,18); V##19=pk2_(_q,19); } while(0)
#define K20(V) asm volatile("" : \
    "+v"(V##0),"+v"(V##1),"+v"(V##2),"+v"(V##3),"+v"(V##4), \
    "+v"(V##5),"+v"(V##6),"+v"(V##7),"+v"(V##8),"+v"(V##9), \
    "+v"(V##10),"+v"(V##11),"+v"(V##12),"+v"(V##13),"+v"(V##14), \
    "+v"(V##15),"+v"(V##16),"+v"(V##17),"+v"(V##18),"+v"(V##19))

// one h-pair broadcast (readlane->SGPR, SALU pack) feeding 4 gate dots
#define ACCP(M) do { \
    unsigned _lo = (unsigned)__builtin_amdgcn_readlane(hb, 2*(M)); \
    unsigned _hi = (unsigned)__builtin_amdgcn_readlane(hb, 2*(M)+1); \
    unsigned _hp = _lo | (_hi << 16); \
    ai = dot2_(_hp, w##M,  ai); af = dot2_(_hp, wf##M, af); \
    ag = dot2_(_hp, wg##M, ag); ao = dot2_(_hp, wo##M, ao); \
} while(0)

// Wave roles (192 thr = 3 waves):
//   wave 0/1: LSTM cell per direction — lane k holds unit k's 4 W_hh rows as
//             80 packed-f16 u32 scalars; h feedback via readlane of f16 bits.
//   wave 2:   logits — reads f16 h-ring (uniform broadcast), 20 dot2/row;
//             one barrier per 32 steps, double-buffered ring.
extern "C" __global__ void __launch_bounds__(NTHR, 1)
bilstm_kernel(const int* __restrict__ tokens,
              const float* __restrict__ embed,
              const float* __restrict__ W_ih1, const float* __restrict__ W_hh1,
              const float* __restrict__ b_ih1, const float* __restrict__ b_hh1,
              const float* __restrict__ W_ih2, const float* __restrict__ W_hh2,
              const float* __restrict__ b_ih2, const float* __restrict__ b_hh2,
              const float* __restrict__ W_l1,  const float* __restrict__ b_l1,
              const float* __restrict__ W_l2,  const float* __restrict__ b_l2,
              float* __restrict__ out)
{
    __shared__ __align__(16) float  tab[2 * NV * NH * 4];   // [d][v][k][gate] f32
    __shared__ __align__(16) unsigned short ring16[2][2][SS][64]; // f16 h ring
    __shared__ __align__(16) float  embS[NV * NE];
    __shared__ int tokS[2][SPC];

    const int tid  = threadIdx.x;
    const int wave = tid >> 6;
    const int lane = tid & 63;
    const int a    = blockIdx.x * CHUNK;

    // ---- stage embed + tokens ----
    for (int p = tid; p < NV * NE; p += NTHR) embS[p] = embed[p];
    for (int p = tid; p < SPC; p += NTHR) {
        int t = a - WARM + p;
        if (t >= 0) {
            tokS[0][p] = tokens[t];
            tokS[1][p] = tokens[T_LEN - 1 - t];
        }
    }
    __syncthreads();

    // ---- x-pre tables: tab[((d*NV+v)*NH+k)*4+g] = emb[v]·W_ih[g*NH+k] + b_ih+b_hh ----
    for (int p = tid; p < 2 * NV * NG; p += NTHR) {
        int g = p & 3, r = p >> 2;
        int k = r % NH, q = r / NH;
        int v = q % NV, dd = q / NV;
        const float* Wih = dd ? W_ih2 : W_ih1;
        const float* bi  = dd ? b_ih2 : b_ih1;
        const float* bh  = dd ? b_hh2 : b_hh1;
        int j = g * NH + k;
        float acc = bi[j] + bh[j];
        #pragma unroll
        for (int e = 0; e < NE; ++e) acc += embS[v * NE + e] * Wih[j * NE + e];
        tab[p] = acc;
    }

    // ---- per-wave weights: packed f16 pairs in named scalar registers ----
    const bool isCell = (wave < 2);
    const int  dir    = wave;
    const int  kk     = (lane < NH) ? lane : NH - 1;

    D20(w); D20(wf); D20(wg); D20(wo);   // w shared: cell i-gate / logit row
    float lb = 0.f;
    if (isCell) {
        const float* Whh = dir ? W_hh2 : W_hh1;
        L20(w,  Whh + (0 * NH + kk) * NH);
        L20(wf, Whh + (1 * NH + kk) * NH);
        L20(wg, Whh + (2 * NH + kk) * NH);
        L20(wo, Whh + (3 * NH + kk) * NH);
        K20(w); K20(wf); K20(wg); K20(wo);
        __builtin_amdgcn_s_setprio(1);   // cell waves are the critical path
    } else {
        int half = lane >> 5, v = lane & 31;
        int vv   = (v < NV) ? v : NV - 1;
        const float* Wl = half ? W_l2 : W_l1;
        L20(w, Wl + vv * NH);
        K20(w);
        if (!half) lb = b_l1[vv] + b_l2[vv];
    }
    __syncthreads();   // tab + tokS ready

    // ---- cell init + first x-pre prefetch ----
    const int cell_ss0 = (a < WARM) ? WUSS : 0;  // block 0 starts exactly at s=WARM
    int   hb = 0;                                 // f16 bits of own h
    float c  = 0.f;
    float x0 = 0.f, x1 = 0.f, x2 = 0.f, x3 = 0.f;
    if (isCell) {
        int tk = tokS[dir][cell_ss0 * SS];
        float4 xv = *(const float4*)&tab[((dir * NV + tk) * NH + kk) * 4];
        x0 = xv.x; x1 = xv.y; x2 = xv.z; x3 = xv.w;
    }

    // ---- main loop: NSS super-steps of SS steps + 1 logit flush ----
    #pragma unroll 1
    for (int ss = 0; ss <= NSS; ++ss) {
        if (isCell && ss >= cell_ss0 && ss < NSS) {
            const int sbase = ss * SS;
            #pragma unroll 1
            for (int sl = 0; sl < SS; ++sl) {
                const int s = sbase + sl;
                float ai = x0, af = x1, ag = x2, ao = x3;
                ACCP(0);  ACCP(1);  ACCP(2);  ACCP(3);  ACCP(4);
                ACCP(5);  ACCP(6);  ACCP(7);  ACCP(8);  ACCP(9);
                ACCP(10); ACCP(11); ACCP(12); ACCP(13); ACCP(14);
                ACCP(15); ACCP(16); ACCP(17); ACCP(18); ACCP(19);
                int sn = (s + 1 < SPC) ? s + 1 : SPC - 1;   // prefetch next x-pre
                int tk = tokS[dir][sn];
                float4 xv = *(const float4*)&tab[((dir * NV + tk) * NH + kk) * 4];
                x0 = xv.x; x1 = xv.y; x2 = xv.z; x3 = xv.w;
                float I = sig_(ai), F = sig_(af), G = tanh_(ag), O = sig_(ao);
                c = fmaf(F, c, I * G);
                float hh = O * tanh_(c);
                hb = (int)__half_as_ushort(__float2half(hh));
                ring16[ss & 1][dir][sl][lane] = (unsigned short)hb;
            }
        }
        if (!isCell && ss > WUSS && ss <= NSS) {
            const int b = ss - 1, par = b & 1;
            const int half = lane >> 5, v = lane & 31;
            #pragma unroll 1
            for (int sl = 0; sl < SS; ++sl) {
                const uint4* hr4 = (const uint4*)ring16[par][half][sl]; // uniform addr
                uint4 u0 = hr4[0], u1 = hr4[1], u2 = hr4[2], u3 = hr4[3], u4 = hr4[4];
                float acc = 0.f;
                acc = dot2_(u0.x, w0,  acc); acc = dot2_(u0.y, w1,  acc);
                acc = dot2_(u0.z, w2,  acc); acc = dot2_(u0.w, w3,  acc);
                acc = dot2_(u1.x, w4,  acc); acc = dot2_(u1.y, w5,  acc);
                acc = dot2_(u1.z, w6,  acc); acc = dot2_(u1.w, w7,  acc);
                acc = dot2_(u2.x, w8,  acc); acc = dot2_(u2.y, w9,  acc);
                acc = dot2_(u2.z, w10, acc); acc = dot2_(u2.w, w11, acc);
                acc = dot2_(u3.x, w12, acc); acc = dot2_(u3.y, w13, acc);
                acc = dot2_(u3.z, w14, acc); acc = dot2_(u3.w, w15, acc);
                acc = dot2_(u4.x, w16, acc); acc = dot2_(u4.y, w17, acc);
                acc = dot2_(u4.z, w18, acc); acc = dot2_(u4.w, w19, acc);
                float oth = __shfl_xor(acc, 32, 64);
                if (half == 0 && v < NV) {
                    int trow = a + b * SS + sl - WARM;
                    out[(size_t)trow * NV + v] = acc + oth + lb;
                }
            }
        }
        __syncthreads();
    }
}

extern "C" void kernel_launch(void* const* d_in, const int* in_sizes, int n_in,
                              void* d_out, int out_size, void* d_ws, size_t ws_size,
                              hipStream_t stream)
{
    const int*   tokens = (const int*)  d_in[0];
    const float* embed  = (const float*)d_in[1];
    const float* W_ih1  = (const float*)d_in[2];
    const float* W_hh1  = (const float*)d_in[3];
    const float* b_ih1  = (const float*)d_in[4];
    const float* b_hh1  = (const float*)d_in[5];
    const float* W_ih2  = (const float*)d_in[6];
    const float* W_hh2  = (const float*)d_in[7];
    const float* b_ih2  = (const float*)d_in[8];
    const float* b_hh2  = (const float*)d_in[9];
    const float* W_l1   = (const float*)d_in[10];
    const float* b_l1   = (const float*)d_in[11];
    const float* W_l2   = (const float*)d_in[12];
    const float* b_l2   = (const float*)d_in[13];
    float* outp = (float*)d_out;

    hipLaunchKernelGGL(bilstm_kernel, dim3(NBLK), dim3(NTHR), 0, stream,
                       tokens, embed, W_ih1, W_hh1, b_ih1, b_hh1,
                       W_ih2, W_hh2, b_ih2, b_hh2, W_l1, b_l1, W_l2, b_l2, outp);
}